// Round 1
// baseline (387.051 us; speedup 1.0000x reference)
//
#include <hip/hip_runtime.h>
#include <math.h>

// Multi-scale region distillation loss — v3 (latency-bound fix).
// Same work decomposition as v2 (32 pixel-groups/block, 1360 blocks), but:
//  * 256-thread blocks (4 waves): wave w covers channels [32w,32w+32) in two
//    passes (+0, +128). Finer residency quantization -> 6 blocks/CU, the whole
//    grid is one co-resident round (1360 <= 1536).
//  * Loads issued in forced 8-deep batches (4 f + 4 fo float4) with
//    __builtin_amdgcn_sched_barrier(0) between the load group and the FMAs,
//    so the compiler cannot collapse memory-level parallelism (v2 showed
//    VGPR=52 < the 64 needed for the intended batch -> serialized loads).

#define EPSV 1e-8f

__global__ __launch_bounds__(256, 6)
void msrd_main(const float* __restrict__ f0, const float* __restrict__ fo0,
               const float* __restrict__ f1, const float* __restrict__ fo1,
               const float* __restrict__ f2, const float* __restrict__ fo2,
               const float* __restrict__ f3, const float* __restrict__ fo3,
               const int*   __restrict__ labels,
               const int*   __restrict__ p_nclass,
               float* __restrict__ ws)
{
    int bid = blockIdx.x;
    int scale, lb, logW, logHW, sshift;
    const float *f, *fo;
    // blocks (32 groups each): [0,1024) s0, [1024,1280) s1, [1280,1344) s2, [1344,1360) s3
    if (bid < 1024)      { scale = 0; lb = bid;        f = f0; fo = fo0; logW = 7; logHW = 14; sshift = 2; }
    else if (bid < 1280) { scale = 1; lb = bid - 1024; f = f1; fo = fo1; logW = 6; logHW = 12; sshift = 3; }
    else if (bid < 1344) { scale = 2; lb = bid - 1280; f = f2; fo = fo2; logW = 5; logHW = 10; sshift = 4; }
    else                 { scale = 3; lb = bid - 1344; f = f3; fo = fo3; logW = 4; logHW = 8;  sshift = 5; }
    const int HW = 1 << logHW;
    const int W  = 1 << logW;

    const int tid  = threadIdx.x;
    const int wave = tid >> 6;    // 0..3
    const int lane = tid & 63;
    const int half = lane >> 5;   // which 16-channel half of the wave's 32-chan chunk
    const int gi   = lane & 31;   // pixel-group index within block

    const int g   = lb * 32 + gi;     // pixel-group index within scale
    const int pix = g << 2;           // flat pixel base (b*HW + h*W + w), w % 4 == 0
    const int b   = pix >> logHW;     // whole half-wave stays within one image
    const int rem = pix & (HW - 1);

    float dx=0.f,dy=0.f,dz=0.f,dw=0.f;
    float ax=0.f,ay=0.f,az=0.f,aw=0.f;
    float bx=0.f,by=0.f,bz=0.f,bw=0.f;

    // 2 passes x 4 batches x 4 channels = 32 channels per thread (x2 tensors).
    #pragma unroll
    for (int pass = 0; pass < 2; ++pass) {
        const int c0 = wave * 32 + half * 16 + pass * 128;
        const float* __restrict__ fpb  = f  + (((size_t)(b * 256 + c0)) << logHW) + rem;
        const float* __restrict__ fopb = fo + (((size_t)(b * 256 + c0)) << logHW) + rem;
        #pragma unroll
        for (int batch = 0; batch < 4; ++batch) {
            const size_t cb = (size_t)(batch * 4) << logHW;
            float4 X0, X1, X2, X3, Y0, Y1, Y2, Y3;
            X0 = *(const float4*)(fpb  + cb);
            X1 = *(const float4*)(fpb  + cb + ((size_t)1 << logHW));
            X2 = *(const float4*)(fpb  + cb + ((size_t)2 << logHW));
            X3 = *(const float4*)(fpb  + cb + ((size_t)3 << logHW));
            Y0 = *(const float4*)(fopb + cb);
            Y1 = *(const float4*)(fopb + cb + ((size_t)1 << logHW));
            Y2 = *(const float4*)(fopb + cb + ((size_t)2 << logHW));
            Y3 = *(const float4*)(fopb + cb + ((size_t)3 << logHW));
            // Fence: all 8 loads must be issued before any consumption below.
            __builtin_amdgcn_sched_barrier(0);
            dx = fmaf(X0.x, Y0.x, dx); dy = fmaf(X0.y, Y0.y, dy);
            dz = fmaf(X0.z, Y0.z, dz); dw = fmaf(X0.w, Y0.w, dw);
            ax = fmaf(X0.x, X0.x, ax); ay = fmaf(X0.y, X0.y, ay);
            az = fmaf(X0.z, X0.z, az); aw = fmaf(X0.w, X0.w, aw);
            bx = fmaf(Y0.x, Y0.x, bx); by = fmaf(Y0.y, Y0.y, by);
            bz = fmaf(Y0.z, Y0.z, bz); bw = fmaf(Y0.w, Y0.w, bw);

            dx = fmaf(X1.x, Y1.x, dx); dy = fmaf(X1.y, Y1.y, dy);
            dz = fmaf(X1.z, Y1.z, dz); dw = fmaf(X1.w, Y1.w, dw);
            ax = fmaf(X1.x, X1.x, ax); ay = fmaf(X1.y, X1.y, ay);
            az = fmaf(X1.z, X1.z, az); aw = fmaf(X1.w, X1.w, aw);
            bx = fmaf(Y1.x, Y1.x, bx); by = fmaf(Y1.y, Y1.y, by);
            bz = fmaf(Y1.z, Y1.z, bz); bw = fmaf(Y1.w, Y1.w, bw);

            dx = fmaf(X2.x, Y2.x, dx); dy = fmaf(X2.y, Y2.y, dy);
            dz = fmaf(X2.z, Y2.z, dz); dw = fmaf(X2.w, Y2.w, dw);
            ax = fmaf(X2.x, X2.x, ax); ay = fmaf(X2.y, X2.y, ay);
            az = fmaf(X2.z, X2.z, az); aw = fmaf(X2.w, X2.w, aw);
            bx = fmaf(Y2.x, Y2.x, bx); by = fmaf(Y2.y, Y2.y, by);
            bz = fmaf(Y2.z, Y2.z, bz); bw = fmaf(Y2.w, Y2.w, bw);

            dx = fmaf(X3.x, Y3.x, dx); dy = fmaf(X3.y, Y3.y, dy);
            dz = fmaf(X3.z, Y3.z, dz); dw = fmaf(X3.w, Y3.w, dw);
            ax = fmaf(X3.x, X3.x, ax); ay = fmaf(X3.y, X3.y, ay);
            az = fmaf(X3.z, X3.z, az); aw = fmaf(X3.w, X3.w, aw);
            bx = fmaf(Y3.x, Y3.x, bx); by = fmaf(Y3.y, Y3.y, by);
            bz = fmaf(Y3.z, Y3.z, bz); bw = fmaf(Y3.w, Y3.w, bw);
        }
    }

    // combine 16-channel halves: xor-32 butterfly over the 12 partials
    dx += __shfl_xor(dx, 32); dy += __shfl_xor(dy, 32);
    dz += __shfl_xor(dz, 32); dw += __shfl_xor(dw, 32);
    ax += __shfl_xor(ax, 32); ay += __shfl_xor(ay, 32);
    az += __shfl_xor(az, 32); aw += __shfl_xor(aw, 32);
    bx += __shfl_xor(bx, 32); by += __shfl_xor(by, 32);
    bz += __shfl_xor(bz, 32); bw += __shfl_xor(bw, 32);

    __shared__ float4 sD[4][32], sA[4][32], sB[4][32];
    __shared__ float bin_sim[32], bin_cnt[32];
    if (tid < 32) { bin_sim[tid] = 0.f; bin_cnt[tid] = 0.f; }
    if (half == 0) {
        sD[wave][gi] = make_float4(dx,dy,dz,dw);
        sA[wave][gi] = make_float4(ax,ay,az,aw);
        sB[wave][gi] = make_float4(bx,by,bz,bw);
    }
    __syncthreads();

    if (tid < 32) {  // wave 0, half 0: lane gi finalizes group gi (its own b/rem)
        float4 D = sD[0][gi], A = sA[0][gi], Bv = sB[0][gi];
        #pragma unroll
        for (int w = 1; w < 4; ++w) {
            float4 t;
            t = sD[w][gi]; D.x += t.x; D.y += t.y; D.z += t.z; D.w += t.w;
            t = sA[w][gi]; A.x += t.x; A.y += t.y; A.z += t.z; A.w += t.w;
            t = sB[w][gi]; Bv.x += t.x; Bv.y += t.y; Bv.z += t.z; Bv.w += t.w;
        }
        const int nclass  = *p_nclass;
        const int labbase = b << 18;  // b * 512 * 512
        float Dv[4] = {D.x, D.y, D.z, D.w};
        float Av[4] = {A.x, A.y, A.z, A.w};
        float Bw[4] = {Bv.x, Bv.y, Bv.z, Bv.w};
        #pragma unroll
        for (int j = 0; j < 4; ++j) {
            float na  = fmaxf(sqrtf(Av[j]), EPSV);
            float nb  = fmaxf(sqrtf(Bw[j]), EPSV);
            float sim = Dv[j] / (na * nb);
            int p    = rem + j;            // stays within row: rem%4==0, W%4==0
            int h    = p >> logW;
            int col  = p & (W - 1);
            int lidx = labbase + ((h << sshift) << 9) + (col << sshift);
            int lab  = labels[lidx];
            if ((unsigned)lab < (unsigned)nclass) {
                atomicAdd(&bin_sim[lab], sim);
                atomicAdd(&bin_cnt[lab], 1.0f);
            }
        }
    }
    __syncthreads();

    if (tid < 32) {
        float s = bin_sim[tid], c = bin_cnt[tid];
        if (s != 0.f || c != 0.f) {
            atomicAdd(&ws[scale * 64 + tid],      s);
            atomicAdd(&ws[scale * 64 + 32 + tid], c);
        }
    }
}

__global__ void msrd_final(const float* __restrict__ ws,
                           const int* __restrict__ p_nclass,
                           const int* __restrict__ p_nold,
                           float* __restrict__ out)
{
    if (threadIdx.x == 0 && blockIdx.x == 0) {
        const int nc = *p_nclass;
        const int no = *p_nold;
        const float wgt[4] = {1.f, 2.f, 3.f, 4.f};
        float loss = 0.f;
        for (int s = 0; s < 4; ++s) {
            float sl = 0.f;
            for (int c = 0; c < nc && c < 32; ++c) {
                float seg = ws[s * 64 + c];
                float cnt = ws[s * 64 + 32 + c];
                if (cnt > 0.f) {
                    float factor = (c == 0) ? (float)no / (float)nc
                                            : (c <= no ? 1.f : 0.f);
                    sl += factor * (1.f - seg / fmaxf(cnt, 1.f));
                }
            }
            loss += wgt[s] * sl;
        }
        out[0] = loss;
    }
}

extern "C" void kernel_launch(void* const* d_in, const int* in_sizes, int n_in,
                              void* d_out, int out_size, void* d_ws, size_t ws_size,
                              hipStream_t stream) {
    // setup_inputs order: pseudo_labels, f0, fo0, f1, fo1, f2, fo2, f3, fo3, num_class, num_old_class
    const int*   labels = (const int*)  d_in[0];
    const float* f0  = (const float*)d_in[1];
    const float* fo0 = (const float*)d_in[2];
    const float* f1  = (const float*)d_in[3];
    const float* fo1 = (const float*)d_in[4];
    const float* f2  = (const float*)d_in[5];
    const float* fo2 = (const float*)d_in[6];
    const float* f3  = (const float*)d_in[7];
    const float* fo3 = (const float*)d_in[8];
    const int* p_nclass = (const int*)d_in[9];
    const int* p_nold   = (const int*)d_in[10];
    float* out = (float*)d_out;
    float* ws  = (float*)d_ws;

    hipMemsetAsync(ws, 0, 4 * 64 * sizeof(float), stream);
    msrd_main<<<dim3(1360), dim3(256), 0, stream>>>(f0, fo0, f1, fo1, f2, fo2, f3, fo3,
                                                    labels, p_nclass, ws);
    msrd_final<<<dim3(1), dim3(64), 0, stream>>>(ws, p_nclass, p_nold, out);
}